// Round 2
// baseline (542.720 us; speedup 1.0000x reference)
//
#include <hip/hip_runtime.h>
#include <math.h>

#define BLOCK   384
#define I_CAPS  1152
#define O_CAPS  32
#define D_DIM   16
#define ROWS    3          // I_CAPS / BLOCK
#define K_SEL   922        // ceil(0.8 * 1152)
#define NWAVES  6          // BLOCK / 64
#define STAGE_ITERS 12     // I_CAPS / (BLOCK/4)

__device__ __forceinline__ float wave_reduce_sum(float v) {
    #pragma unroll
    for (int off = 32; off > 0; off >>= 1) v += __shfl_down(v, off);
    return v;
}

__global__ __launch_bounds__(BLOCK, 3)
void subset_routing_kernel(const float* __restrict__ u, float* __restrict__ out) {
    // column-major tile: tile[d][i] -> LDS bank = i % 32 (1152 % 32 == 0),
    // so per-thread row readback (lane t reads tile[d][t]) is 2-way aliased = free.
    __shared__ float tile[D_DIM][I_CAPS];          // 72 KB
    __shared__ float red[NWAVES][17];
    __shared__ float sh_v[D_DIM];
    __shared__ int   hist[256];
    __shared__ unsigned sh_prefix;
    __shared__ int   sh_k;

    const int t    = threadIdx.x;
    const int lane = t & 63;
    const int wave = t >> 6;

    // block -> (b,o): pair (b,2j) and (b,2j+1) land on the same XCD (mod-8)
    int X = blockIdx.x;
    int r = X & 7;
    int m = (X >> 3) & 1;
    int q = X >> 4;
    int p = q * 8 + r;            // pair id in [0,2048)
    int b = p >> 4;               // [0,128)
    int o = ((p & 15) << 1) | m;  // [0,32)

    const size_t base = (((size_t)b * I_CAPS) * O_CAPS + (size_t)o) * D_DIM;

    // ---- coalesced staging: 4 lanes per row, each lane one float4 ----
    // per wave-instruction: 16 unique 64B lines (no redundancy); all 12
    // loads issued before the first wait -> deep MLP.
    const int rsub = t >> 2;      // 0..95
    const int c    = t & 3;       // float4 chunk within row
    float4 g[STAGE_ITERS];
    #pragma unroll
    for (int it = 0; it < STAGE_ITERS; ++it) {
        int row = it * 96 + rsub;
        g[it] = *(const float4*)(u + base + (size_t)row * (O_CAPS * D_DIM) + c * 4);
    }
    #pragma unroll
    for (int it = 0; it < STAGE_ITERS; ++it) {
        int row = it * 96 + rsub;
        tile[c * 4 + 0][row] = g[it].x;
        tile[c * 4 + 1][row] = g[it].y;
        tile[c * 4 + 2][row] = g[it].z;
        tile[c * 4 + 3][row] = g[it].w;
    }
    __syncthreads();

    // ---- pull 3 rows into registers (conflict-free: bank = t % 32, 2-way) ----
    float uu[ROWS][D_DIM];
    float nn[ROWS];
    #pragma unroll
    for (int rr = 0; rr < ROWS; ++rr) {
        int i = t + rr * BLOCK;
        #pragma unroll
        for (int d = 0; d < D_DIM; ++d) uu[rr][d] = tile[d][i];
    }

    // ---- per-row norms + partial weighted sums ----
    float num_acc[D_DIM];
    #pragma unroll
    for (int d = 0; d < D_DIM; ++d) num_acc[d] = 0.f;
    float den_acc = 0.f;
    #pragma unroll
    for (int rr = 0; rr < ROWS; ++rr) {
        float s = 0.f;
        #pragma unroll
        for (int d = 0; d < D_DIM; ++d) s += uu[rr][d] * uu[rr][d];
        nn[rr] = sqrtf(s);
        den_acc += nn[rr];
        #pragma unroll
        for (int d = 0; d < D_DIM; ++d) num_acc[d] += uu[rr][d] * nn[rr];
    }

    // ---- block reduction: v = num/den ----
    #pragma unroll
    for (int d = 0; d < D_DIM; ++d) {
        float s = wave_reduce_sum(num_acc[d]);
        if (lane == 0) red[wave][d] = s;
    }
    {
        float s = wave_reduce_sum(den_acc);
        if (lane == 0) red[wave][16] = s;
    }
    __syncthreads();
    if (t < D_DIM) {
        float tot = 0.f, dtot = 0.f;
        #pragma unroll
        for (int w = 0; w < NWAVES; ++w) { tot += red[w][t]; dtot += red[w][16]; }
        sh_v[t] = tot / dtot;
    }
    __syncthreads();

    float vv[D_DIM];
    #pragma unroll
    for (int d = 0; d < D_DIM; ++d) vv[d] = sh_v[d];

    // ---- losses -> order-preserving uint keys (kept in registers) ----
    unsigned key[ROWS];
    #pragma unroll
    for (int rr = 0; rr < ROWS; ++rr) {
        float loss = 0.f;
        #pragma unroll
        for (int d = 0; d < D_DIM; ++d) loss += vv[d] * uu[rr][d];
        loss = -loss;
        unsigned bits = __float_as_uint(loss);
        unsigned msk  = ((unsigned)((int)bits >> 31)) | 0x80000000u;
        key[rr] = bits ^ msk;
    }

    // ---- exact k-th smallest via 4-round MSD radix select ----
    unsigned prefix = 0u;
    int kk = K_SEL;
    #pragma unroll
    for (int shift = 24; shift >= 0; shift -= 8) {
        if (t < 256) hist[t] = 0;
        __syncthreads();
        unsigned maskAbove = (shift == 24) ? 0u : (0xFFFFFFFFu << (shift + 8));
        #pragma unroll
        for (int rr = 0; rr < ROWS; ++rr) {
            unsigned k = key[rr];
            if ((k & maskAbove) == prefix)
                atomicAdd(&hist[(k >> shift) & 255u], 1);
        }
        __syncthreads();
        if (wave == 0) {
            int c0 = hist[lane*4+0], c1 = hist[lane*4+1],
                c2 = hist[lane*4+2], c3 = hist[lane*4+3];
            int s = c0 + c1 + c2 + c3;
            int cum = s;
            #pragma unroll
            for (int off = 1; off < 64; off <<= 1) {
                int vsh = __shfl_up(cum, off);
                if (lane >= off) cum += vsh;
            }
            int cumprev = cum - s;
            bool has = (cumprev < kk) && (cum >= kk);
            unsigned long long ball = __ballot(has);
            int win = __ffsll(ball) - 1;
            if (lane == win) {
                int kr = kk - cumprev;
                int digit = 0;
                if (kr > c0) { kr -= c0; digit = 1;
                    if (kr > c1) { kr -= c1; digit = 2;
                        if (kr > c2) { kr -= c2; digit = 3; } } }
                sh_prefix = prefix | ((unsigned)(lane*4 + digit) << shift);
                sh_k = kr;
            }
        }
        __syncthreads();
        prefix = sh_prefix;
        kk = sh_k;
    }
    // prefix == exact k-th smallest key; choose = (key <= prefix)

    // ---- masked weighted average (u, n still in registers) ----
    float num2[D_DIM];
    #pragma unroll
    for (int d = 0; d < D_DIM; ++d) num2[d] = 0.f;
    float den2 = 0.f;
    #pragma unroll
    for (int rr = 0; rr < ROWS; ++rr) {
        float msk = (key[rr] <= prefix) ? 1.0f : 0.0f;
        float w = nn[rr] * msk;
        den2 += w;
        #pragma unroll
        for (int d = 0; d < D_DIM; ++d) num2[d] += uu[rr][d] * w;
    }

    #pragma unroll
    for (int d = 0; d < D_DIM; ++d) {
        float s = wave_reduce_sum(num2[d]);
        if (lane == 0) red[wave][d] = s;
    }
    {
        float s = wave_reduce_sum(den2);
        if (lane == 0) red[wave][16] = s;
    }
    __syncthreads();
    if (t < D_DIM) {
        float tot = 0.f, dtot = 0.f;
        #pragma unroll
        for (int w = 0; w < NWAVES; ++w) { tot += red[w][t]; dtot += red[w][16]; }
        out[(((size_t)b * O_CAPS) + o) * D_DIM + t] = tot / dtot;
    }
}

extern "C" void kernel_launch(void* const* d_in, const int* in_sizes, int n_in,
                              void* d_out, int out_size, void* d_ws, size_t ws_size,
                              hipStream_t stream) {
    const float* u = (const float*)d_in[0];
    float* out = (float*)d_out;
    const int B = 128;
    subset_routing_kernel<<<dim3(B * O_CAPS), dim3(BLOCK), 0, stream>>>(u, out);
}

// Round 3
// 444.786 us; speedup vs baseline: 1.2202x; 1.2202x over previous
//
#include <hip/hip_runtime.h>
#include <math.h>

#define BLOCK   384
#define I_CAPS  1152
#define O_CAPS  32
#define D_DIM   16
#define RPT     12         // quarter-rows (float4 chunks) per thread
#define K_SEL4  3688       // 4 * ceil(0.8 * 1152)  (keys replicated x4 in hist)
#define NWAVES  6

// intra-quad xor shuffles as DPP (VALU pipe, not LDS)
__device__ __forceinline__ float dpp_xor1(float x) {
    return __int_as_float(__builtin_amdgcn_mov_dpp(__float_as_int(x), 0xB1, 0xF, 0xF, true));
}
__device__ __forceinline__ float dpp_xor2(float x) {
    return __int_as_float(__builtin_amdgcn_mov_dpp(__float_as_int(x), 0x4E, 0xF, 0xF, true));
}

__global__ __launch_bounds__(BLOCK, 5)
void subset_routing_kernel(const float* __restrict__ u, float* __restrict__ out) {
    __shared__ float sh_num[NWAVES][16];
    __shared__ float sh_den[NWAVES];
    __shared__ float sh_v[D_DIM];
    __shared__ int   hist[256];
    __shared__ unsigned sh_prefix;
    __shared__ int   sh_k;

    const int t    = threadIdx.x;
    const int lane = t & 63;
    const int wave = t >> 6;
    const int c    = t & 3;    // d-chunk (quad lane)
    const int s    = t >> 2;   // row-subgroup 0..95

    // block -> (b,o): pair (b,2j)/(b,2j+1) on same XCD so 128B lines are shared
    int X = blockIdx.x;
    int r8 = X & 7, mm = (X >> 3) & 1, q8 = X >> 4;
    int p  = q8 * 8 + r8;
    int b  = p >> 4;
    int o  = ((p & 15) << 1) | mm;

    const float* base = u + (((size_t)b * I_CAPS) * O_CAPS + (size_t)o) * D_DIM + c * 4;

    // coalesced: per wave-load, 16 rows x 64B contiguous chunks
    float4 q[RPT];
    #pragma unroll
    for (int r = 0; r < RPT; ++r)
        q[r] = *(const float4*)(base + (size_t)(r * 96 + s) * (O_CAPS * D_DIM));

    // ---- phase A: norms + weighted sums (norms via quad DPP xor) ----
    float ax = 0.f, ay = 0.f, az = 0.f, aw = 0.f, dn = 0.f;
    #pragma unroll
    for (int r = 0; r < RPT; ++r) {
        float ss = q[r].x*q[r].x + q[r].y*q[r].y + q[r].z*q[r].z + q[r].w*q[r].w;
        ss += dpp_xor1(ss); ss += dpp_xor2(ss);     // full row ||u||^2 in all 4 lanes
        float n = sqrtf(ss);
        ax += q[r].x * n; ay += q[r].y * n; az += q[r].z * n; aw += q[r].w * n;
        dn += n;                                    // counted x4 across quad; /4 later
    }
    #pragma unroll
    for (int off = 4; off < 64; off <<= 1) {        // reduce over same-c lanes
        ax += __shfl_down(ax, off); ay += __shfl_down(ay, off);
        az += __shfl_down(az, off); aw += __shfl_down(aw, off);
        dn += __shfl_down(dn, off);
    }
    dn += dpp_xor1(dn); dn += dpp_xor2(dn);         // fold quad for den
    if (lane < 4) {
        float* dst = &sh_num[wave][lane * 4];
        dst[0] = ax; dst[1] = ay; dst[2] = az; dst[3] = aw;
    }
    if (lane == 0) sh_den[wave] = dn;
    __syncthreads();
    if (t < D_DIM) {
        float nm = 0.f, dd = 0.f;
        #pragma unroll
        for (int w = 0; w < NWAVES; ++w) { nm += sh_num[w][t]; dd += sh_den[w]; }
        sh_v[t] = nm / (dd * 0.25f);
    }
    __syncthreads();
    float4 v4 = make_float4(sh_v[c*4+0], sh_v[c*4+1], sh_v[c*4+2], sh_v[c*4+3]);

    // ---- keys: loss = -<v,u_i>, order-preserving uint (all quad lanes hold it) ----
    unsigned key[RPT];
    #pragma unroll
    for (int r = 0; r < RPT; ++r) {
        float dl = v4.x*q[r].x + v4.y*q[r].y + v4.z*q[r].z + v4.w*q[r].w;
        dl += dpp_xor1(dl); dl += dpp_xor2(dl);
        unsigned bits = __float_as_uint(-dl);
        key[r] = bits ^ (((unsigned)((int)bits >> 31)) | 0x80000000u);
    }

    // ---- exact k-th smallest: 4-round MSD radix select over x4-replicated keys ----
    unsigned prefix = 0u;
    int kk = K_SEL4;
    #pragma unroll
    for (int shift = 24; shift >= 0; shift -= 8) {
        if (t < 256) hist[t] = 0;
        __syncthreads();
        unsigned maskAbove = (shift == 24) ? 0u : (0xFFFFFFFFu << (shift + 8));
        #pragma unroll
        for (int r = 0; r < RPT; ++r) {
            unsigned k = key[r];
            if ((k & maskAbove) == prefix)
                atomicAdd(&hist[(k >> shift) & 255u], 1);
        }
        __syncthreads();
        if (wave == 0) {
            int c0 = hist[lane*4+0], c1 = hist[lane*4+1],
                c2 = hist[lane*4+2], c3 = hist[lane*4+3];
            int sm = c0 + c1 + c2 + c3;
            int cum = sm;
            #pragma unroll
            for (int off = 1; off < 64; off <<= 1) {
                int vsh = __shfl_up(cum, off);
                if (lane >= off) cum += vsh;
            }
            int cumprev = cum - sm;
            bool has = (cumprev < kk) && (cum >= kk);
            unsigned long long ball = __ballot(has);
            int win = __ffsll(ball) - 1;
            if (lane == win) {
                int kr = kk - cumprev;
                int digit = 0;
                if (kr > c0) { kr -= c0; digit = 1;
                    if (kr > c1) { kr -= c1; digit = 2;
                        if (kr > c2) { kr -= c2; digit = 3; } } }
                sh_prefix = prefix | ((unsigned)(lane*4 + digit) << shift);
                sh_k = kr;
            }
        }
        __syncthreads();
        prefix = sh_prefix;
        kk = sh_k;
    }
    // prefix == exact k-th smallest key; choose = (key <= prefix)

    // ---- phase E: masked weighted average (recompute n, zero extra regs) ----
    float ex = 0.f, ey = 0.f, ez = 0.f, ew = 0.f, d2 = 0.f;
    #pragma unroll
    for (int r = 0; r < RPT; ++r) {
        float ss = q[r].x*q[r].x + q[r].y*q[r].y + q[r].z*q[r].z + q[r].w*q[r].w;
        ss += dpp_xor1(ss); ss += dpp_xor2(ss);
        float n = sqrtf(ss);
        float w = (key[r] <= prefix) ? n : 0.f;
        ex += q[r].x * w; ey += q[r].y * w; ez += q[r].z * w; ew += q[r].w * w;
        d2 += w;
    }
    #pragma unroll
    for (int off = 4; off < 64; off <<= 1) {
        ex += __shfl_down(ex, off); ey += __shfl_down(ey, off);
        ez += __shfl_down(ez, off); ew += __shfl_down(ew, off);
        d2 += __shfl_down(d2, off);
    }
    d2 += dpp_xor1(d2); d2 += dpp_xor2(d2);
    if (lane < 4) {
        float* dst = &sh_num[wave][lane * 4];
        dst[0] = ex; dst[1] = ey; dst[2] = ez; dst[3] = ew;
    }
    if (lane == 0) sh_den[wave] = d2;
    __syncthreads();
    if (t < D_DIM) {
        float nm = 0.f, dd = 0.f;
        #pragma unroll
        for (int w = 0; w < NWAVES; ++w) { nm += sh_num[w][t]; dd += sh_den[w]; }
        out[((size_t)b * O_CAPS + o) * D_DIM + t] = nm / (dd * 0.25f);
    }
}

extern "C" void kernel_launch(void* const* d_in, const int* in_sizes, int n_in,
                              void* d_out, int out_size, void* d_ws, size_t ws_size,
                              hipStream_t stream) {
    const float* u = (const float*)d_in[0];
    float* out = (float*)d_out;
    const int B = 128;
    subset_routing_kernel<<<dim3(B * O_CAPS), dim3(BLOCK), 0, stream>>>(u, out);
}